// Round 1
// baseline (42.072 us; speedup 1.0000x reference)
//
#include <hip/hip_runtime.h>
#include <math.h>

// PhaseLoss: ip + gd + ptd phase losses over [32,1,513,512] fp32 spectra.
// d'[b,f,t] = angle(ref * conj(est))  (== phase_r - phase_g mod 2pi; unwrap is
// mod-2pi invariant so this halves the atan2 count and bounds |d'| <= pi).
// ip  = |d'|
// gd  = unwrap(d'[f-1] - d'[f])   (f-1 < 0 -> neighbor 0)
// ptd = unwrap(d'[t-1] - d'[t])   (t-1 < 0 -> neighbor 0)
// output scalar = (sum of all three terms) / (B*F*T)

#define NB 32
#define NF 513
#define NT 512
#define TILE_F 8
#define TILE_T 128
#define THREADS_X 32
#define NSLOTS 2048

static __device__ __forceinline__ float pdiff(float a, float b, float c, float d) {
    // est = a + i*b ; ref = c + i*d ; angle(ref * conj(est)) = atan2(d*a - c*b, c*a + d*b)
    return atan2f(fmaf(d, a, -(c * b)), fmaf(c, a, d * b));
}

static __device__ __forceinline__ float wrap_abs(float x) {
    // |x - 2pi*round(x/2pi)| for |x| < 2pi  (x is a difference of principal angles)
    const float PI_F     = 3.14159274101257324f;   // 0x40490FDB
    const float TWO_PI_F = 6.28318548202514648f;   // exactly 2*PI_F
    float u = fabsf(x);
    return u > PI_F ? TWO_PI_F - u : u;
}

__global__ void zero_slots_k(float* __restrict__ slots) {
    for (int i = threadIdx.x; i < NSLOTS; i += blockDim.x)
        slots[i] = 0.f;
}

__global__ __launch_bounds__(256) void phase_loss_k(
    const float* __restrict__ er, const float* __restrict__ ei,
    const float* __restrict__ rr, const float* __restrict__ ri,
    float* __restrict__ slots)
{
    __shared__ float ds[TILE_F + 1][TILE_T + 1];   // [9][129] fp32, halo at [0][*] and [*][0]
    const int tx  = threadIdx.x;                   // 0..31
    const int ty  = threadIdx.y;                   // 0..7
    const int tid = ty * THREADS_X + tx;
    const int t0  = blockIdx.x * TILE_T;
    const int f0  = blockIdx.y * TILE_F;
    const int b   = blockIdx.z;
    const int base = b * (NF * NT);

    const int f = f0 + ty;
    const bool valid = (f < NF);

    float dv0 = 0.f, dv1 = 0.f, dv2 = 0.f, dv3 = 0.f;
    if (valid) {
        int idx = base + f * NT + t0 + tx * 4;
        float4 a4 = *(const float4*)(er + idx);
        float4 b4 = *(const float4*)(ei + idx);
        float4 c4 = *(const float4*)(rr + idx);
        float4 d4 = *(const float4*)(ri + idx);
        dv0 = pdiff(a4.x, b4.x, c4.x, d4.x);
        dv1 = pdiff(a4.y, b4.y, c4.y, d4.y);
        dv2 = pdiff(a4.z, b4.z, c4.z, d4.z);
        dv3 = pdiff(a4.w, b4.w, c4.w, d4.w);
    }
    ds[ty + 1][tx * 4 + 1] = dv0;
    ds[ty + 1][tx * 4 + 2] = dv1;
    ds[ty + 1][tx * 4 + 3] = dv2;
    ds[ty + 1][tx * 4 + 4] = dv3;

    // top halo row (f0-1, t in [t0 .. t0+127]) -- lanes 0..31 of wave 0
    if (tid < 32) {
        float h0 = 0.f, h1 = 0.f, h2 = 0.f, h3 = 0.f;
        if (f0 > 0) {
            int idx = base + (f0 - 1) * NT + t0 + tid * 4;
            float4 a4 = *(const float4*)(er + idx);
            float4 b4 = *(const float4*)(ei + idx);
            float4 c4 = *(const float4*)(rr + idx);
            float4 d4 = *(const float4*)(ri + idx);
            h0 = pdiff(a4.x, b4.x, c4.x, d4.x);
            h1 = pdiff(a4.y, b4.y, c4.y, d4.y);
            h2 = pdiff(a4.z, b4.z, c4.z, d4.z);
            h3 = pdiff(a4.w, b4.w, c4.w, d4.w);
        }
        ds[0][tid * 4 + 1] = h0;
        ds[0][tid * 4 + 2] = h1;
        ds[0][tid * 4 + 3] = h2;
        ds[0][tid * 4 + 4] = h3;
    } else if (tid == 32) {
        // corner (f0-1, t0-1)
        float v = 0.f;
        if (f0 > 0 && t0 > 0) {
            int idx = base + (f0 - 1) * NT + (t0 - 1);
            v = pdiff(er[idx], ei[idx], rr[idx], ri[idx]);
        }
        ds[0][0] = v;
    } else if (tid < 33 + TILE_F) {
        // left halo col (f0+k, t0-1)
        int k = tid - 33;
        int hf = f0 + k;
        float v = 0.f;
        if (t0 > 0 && hf < NF) {
            int idx = base + hf * NT + (t0 - 1);
            v = pdiff(er[idx], ei[idx], rr[idx], ri[idx]);
        }
        ds[k + 1][0] = v;
    }
    __syncthreads();

    float s = 0.f;
    if (valid) {
        float dtm = ds[ty + 1][tx * 4];          // t-1 neighbor of element k=0
        float dvk[4] = {dv0, dv1, dv2, dv3};
        #pragma unroll
        for (int k = 0; k < 4; ++k) {
            float d   = dvk[k];
            float dfm = ds[ty][tx * 4 + 1 + k];  // f-1 neighbor
            s += fabsf(d);                        // ip
            s += wrap_abs(dfm - d);               // gd
            s += wrap_abs(dtm - d);               // ptd
            dtm = d;                              // next t-1 is this element
        }
    }

    // block reduction: wave shuffle, then cross-wave via LDS
    #pragma unroll
    for (int off = 32; off > 0; off >>= 1)
        s += __shfl_down(s, off, 64);
    __shared__ float wsum[4];
    if ((tid & 63) == 0) wsum[tid >> 6] = s;
    __syncthreads();
    if (tid == 0) {
        float tot = wsum[0] + wsum[1] + wsum[2] + wsum[3];
        int lb = (b * gridDim.y + blockIdx.y) * gridDim.x + blockIdx.x;
        atomicAdd(&slots[lb & (NSLOTS - 1)], tot);
    }
}

__global__ __launch_bounds__(256) void finalize_k(const float* __restrict__ slots,
                                                  float* __restrict__ out)
{
    int tid = threadIdx.x;
    float s = 0.f;
    for (int i = tid; i < NSLOTS; i += 256) s += slots[i];
    #pragma unroll
    for (int off = 32; off > 0; off >>= 1)
        s += __shfl_down(s, off, 64);
    __shared__ float wsum[4];
    if ((tid & 63) == 0) wsum[tid >> 6] = s;
    __syncthreads();
    if (tid == 0) {
        double tot = (double)wsum[0] + (double)wsum[1] + (double)wsum[2] + (double)wsum[3];
        out[0] = (float)(tot / (double)((long long)NB * NF * NT));
    }
}

extern "C" void kernel_launch(void* const* d_in, const int* in_sizes, int n_in,
                              void* d_out, int out_size, void* d_ws, size_t ws_size,
                              hipStream_t stream) {
    const float* er = (const float*)d_in[0];  // spec_est_real
    const float* ei = (const float*)d_in[1];  // spec_est_imag
    const float* rr = (const float*)d_in[2];  // spec_ref_real
    const float* ri = (const float*)d_in[3];  // spec_ref_imag
    float* out   = (float*)d_out;
    float* slots = (float*)d_ws;              // NSLOTS fp32 partial-sum slots

    zero_slots_k<<<1, 256, 0, stream>>>(slots);

    dim3 grid(NT / TILE_T, (NF + TILE_F - 1) / TILE_F, NB);  // (4, 65, 32) = 8320 blocks
    dim3 block(THREADS_X, TILE_F);                            // (32, 8) = 256 threads
    phase_loss_k<<<grid, block, 0, stream>>>(er, ei, rr, ri, slots);

    finalize_k<<<1, 256, 0, stream>>>(slots, out);
}

// Round 2
// 36.550 us; speedup vs baseline: 1.1511x; 1.1511x over previous
//
#include <hip/hip_runtime.h>
#include <math.h>

// PhaseLoss: ip + gd + ptd phase losses over [32,1,513,512] fp32 spectra.
// d'[b,f,t] = angle(ref * conj(est))  (== phase_r - phase_g mod 2pi; unwrap is
// mod-2pi invariant so one atan2 per element and |d'| <= pi).
// ip  = |d'|
// gd  = unwrap(d'[f-1,t] - d'[f,t])   (f-1 < 0 -> neighbor 0)
// ptd = unwrap(d'[f,t-1] - d'[f,t])   (t-1 < 0 -> neighbor 0)
// output scalar = (sum of all three) / (B*F*T)
//
// Structure: 512-thread blocks (8 waves). Each wave owns one full f-row
// (lane holds 8 consecutive t's -> t-neighbor is register/shfl_up, no t-halo).
// f-neighbor rows staged in LDS with aligned 32B/lane b128 ops (conflict-free).
// f-halo row (f0-1) recomputed cooperatively: 1 element/thread, coalesced.

#define NB 32
#define NF 513
#define NT 512
#define ROWS 8
#define NSLOTS 2048

static __device__ __forceinline__ float fast_atan2(float y, float x) {
    const float PI_F  = 3.14159274101257324f;
    const float PI_2F = 1.57079632679489662f;
    float ax = fabsf(x), ay = fabsf(y);
    float mx = fmaxf(ax, ay), mn = fminf(ax, ay);
    float r  = mn * __builtin_amdgcn_rcpf(mx);
    r = (mx == 0.f) ? 0.f : r;                 // atan2(0,0) guard
    float s = r * r;
    float p = fmaf(s, -0.01172120f, 0.05265332f);
    p = fmaf(s, p, -0.11643287f);
    p = fmaf(s, p,  0.19354346f);
    p = fmaf(s, p, -0.33262347f);
    p = fmaf(s, p,  0.99997726f);
    float a = r * p;                            // atan(mn/mx) in [0, pi/4]
    a = (ay > ax) ? (PI_2F - a) : a;            // [0, pi/2]
    a = (x < 0.f) ? (PI_F - a) : a;             // [0, pi]
    return copysignf(a, y);
}

static __device__ __forceinline__ float pdiff(float a, float b, float c, float d) {
    // est = a+ib ; ref = c+id ; angle(ref * conj(est)) = atan2(d*a - c*b, c*a + d*b)
    return fast_atan2(fmaf(d, a, -(c * b)), fmaf(c, a, d * b));
}

static __device__ __forceinline__ float wrap_abs(float x) {
    // |x - 2pi*round(x/2pi)| for |x| < 2pi
    const float PI_F     = 3.14159274101257324f;
    const float TWO_PI_F = 6.28318548202514648f;
    float u = fabsf(x);
    return u > PI_F ? TWO_PI_F - u : u;
}

__global__ __launch_bounds__(512) void phase_loss_k(
    const float* __restrict__ er, const float* __restrict__ ei,
    const float* __restrict__ rr, const float* __restrict__ ri,
    float* __restrict__ slots)
{
    __shared__ float ds[ROWS + 1][NT];   // slot 0 = halo row f0-1; slot w+1 = row f0+w
    const int tid  = threadIdx.x;
    const int wave = tid >> 6;
    const int lane = tid & 63;
    const int fc   = blockIdx.x;
    const int b    = blockIdx.y;
    const int f0   = fc * ROWS;
    const int base = b * (NF * NT);
    const int f    = f0 + wave;
    const bool valid = (f < NF);

    // halo row (f0-1): one element per thread, coalesced b32 loads
    {
        float h = 0.f;
        if (f0 > 0) {
            int idx = base + (f0 - 1) * NT + tid;
            h = pdiff(er[idx], ei[idx], rr[idx], ri[idx]);
        }
        ds[0][tid] = h;
    }

    float d[8];
    if (valid) {
        int idx = base + f * NT + lane * 8;
        float4 a0 = *(const float4*)(er + idx);
        float4 a1 = *(const float4*)(er + idx + 4);
        float4 b0 = *(const float4*)(ei + idx);
        float4 b1 = *(const float4*)(ei + idx + 4);
        float4 c0 = *(const float4*)(rr + idx);
        float4 c1 = *(const float4*)(rr + idx + 4);
        float4 e0 = *(const float4*)(ri + idx);
        float4 e1 = *(const float4*)(ri + idx + 4);
        d[0] = pdiff(a0.x, b0.x, c0.x, e0.x);
        d[1] = pdiff(a0.y, b0.y, c0.y, e0.y);
        d[2] = pdiff(a0.z, b0.z, c0.z, e0.z);
        d[3] = pdiff(a0.w, b0.w, c0.w, e0.w);
        d[4] = pdiff(a1.x, b1.x, c1.x, e1.x);
        d[5] = pdiff(a1.y, b1.y, c1.y, e1.y);
        d[6] = pdiff(a1.z, b1.z, c1.z, e1.z);
        d[7] = pdiff(a1.w, b1.w, c1.w, e1.w);
        *(float4*)&ds[wave + 1][lane * 8]     = make_float4(d[0], d[1], d[2], d[3]);
        *(float4*)&ds[wave + 1][lane * 8 + 4] = make_float4(d[4], d[5], d[6], d[7]);
    }
    __syncthreads();

    float s = 0.f;
    if (valid) {
        float4 g0 = *(const float4*)&ds[wave][lane * 8];      // row f-1
        float4 g1 = *(const float4*)&ds[wave][lane * 8 + 4];
        float fm[8] = {g0.x, g0.y, g0.z, g0.w, g1.x, g1.y, g1.z, g1.w};
        float dt = __shfl_up(d[7], 1, 64);                     // t-1 across lane boundary
        if (lane == 0) dt = 0.f;                               // t==0 -> neighbor 0
        #pragma unroll
        for (int k = 0; k < 8; ++k) {
            s += fabsf(d[k]);                // ip
            s += wrap_abs(fm[k] - d[k]);     // gd
            s += wrap_abs(dt - d[k]);        // ptd
            dt = d[k];
        }
    }

    // per-wave reduce, one atomic per wave
    #pragma unroll
    for (int off = 32; off > 0; off >>= 1)
        s += __shfl_down(s, off, 64);
    if (lane == 0) {
        int sl = ((b * gridDim.x + fc) * ROWS + wave) & (NSLOTS - 1);
        atomicAdd(&slots[sl], s);
    }
}

__global__ __launch_bounds__(256) void finalize_k(const float* __restrict__ slots,
                                                  float* __restrict__ out)
{
    int tid = threadIdx.x;
    float s = 0.f;
    for (int i = tid; i < NSLOTS; i += 256) s += slots[i];
    #pragma unroll
    for (int off = 32; off > 0; off >>= 1)
        s += __shfl_down(s, off, 64);
    __shared__ float wsum[4];
    if ((tid & 63) == 0) wsum[tid >> 6] = s;
    __syncthreads();
    if (tid == 0) {
        double tot = (double)wsum[0] + (double)wsum[1] + (double)wsum[2] + (double)wsum[3];
        out[0] = (float)(tot / (double)((long long)NB * NF * NT));
    }
}

extern "C" void kernel_launch(void* const* d_in, const int* in_sizes, int n_in,
                              void* d_out, int out_size, void* d_ws, size_t ws_size,
                              hipStream_t stream) {
    const float* er = (const float*)d_in[0];
    const float* ei = (const float*)d_in[1];
    const float* rr = (const float*)d_in[2];
    const float* ri = (const float*)d_in[3];
    float* out   = (float*)d_out;
    float* slots = (float*)d_ws;

    hipMemsetAsync(slots, 0, NSLOTS * sizeof(float), stream);

    dim3 grid((NF + ROWS - 1) / ROWS, NB);   // (65, 32) = 2080 blocks
    phase_loss_k<<<grid, 512, 0, stream>>>(er, ei, rr, ri, slots);

    finalize_k<<<1, 256, 0, stream>>>(slots, out);
}

// Round 3
// 33.896 us; speedup vs baseline: 1.2412x; 1.0783x over previous
//
#include <hip/hip_runtime.h>
#include <math.h>

// PhaseLoss: ip + gd + ptd phase losses over [32,1,513,512] fp32 spectra.
// d'[b,f,t] = angle(ref * conj(est)); ip = |d'|;
// gd  = unwrap(d'[f-1,t] - d'[f,t])  (f-1<0 -> 0)
// ptd = unwrap(d'[f,t-1] - d'[f,t])  (t-1<0 -> 0)
// out = sum / (B*F*T)
//
// Structure: register-carried f-loop. Each wave owns 8 f-rows x full t-row
// (lane holds 8 consecutive t's). f-neighbor = previous iteration's registers
// (1 halo row recomputed per 8 rows); t-neighbor = register/shfl_up.
// No LDS staging, no __syncthreads in hot path, no atomics, no memset:
// each block writes a unique slot, finalize kernel sums 520 floats.

#define NB 32
#define NF 513
#define NT 512
#define RPW 8
#define CHUNKS 65          // ceil(513/8)
#define NBLOCKS 520        // 32*65 waves / 4 waves per block
#define NTOT 8404992LL     // 32*513*512

static __device__ __forceinline__ float fast_atan2(float y, float x) {
    const float PI_F  = 3.14159274101257324f;
    const float PI_2F = 1.57079632679489662f;
    float ax = fabsf(x), ay = fabsf(y);
    float mx = fmaxf(ax, ay), mn = fminf(ax, ay);
    float r  = mn * __builtin_amdgcn_rcpf(mx);
    r = (mx == 0.f) ? 0.f : r;
    float s = r * r;
    float p = fmaf(s, -0.01172120f, 0.05265332f);
    p = fmaf(s, p, -0.11643287f);
    p = fmaf(s, p,  0.19354346f);
    p = fmaf(s, p, -0.33262347f);
    p = fmaf(s, p,  0.99997726f);
    float a = r * p;
    a = (ay > ax) ? (PI_2F - a) : a;
    a = (x < 0.f) ? (PI_F - a) : a;
    return copysignf(a, y);
}

static __device__ __forceinline__ float pdiff(float a, float b, float c, float d) {
    // est=a+ib, ref=c+id: angle(ref*conj(est)) = atan2(d*a - c*b, c*a + d*b)
    return fast_atan2(fmaf(d, a, -(c * b)), fmaf(c, a, d * b));
}

static __device__ __forceinline__ float wrap_abs(float x) {
    const float PI_F     = 3.14159274101257324f;
    const float TWO_PI_F = 6.28318548202514648f;
    float u = fabsf(x);
    return u > PI_F ? TWO_PI_F - u : u;
}

struct Row8 { float4 a0, a1, b0, b1, c0, c1, e0, e1; };

static __device__ __forceinline__ void calc8(const Row8& r, float d[8]) {
    d[0] = pdiff(r.a0.x, r.b0.x, r.c0.x, r.e0.x);
    d[1] = pdiff(r.a0.y, r.b0.y, r.c0.y, r.e0.y);
    d[2] = pdiff(r.a0.z, r.b0.z, r.c0.z, r.e0.z);
    d[3] = pdiff(r.a0.w, r.b0.w, r.c0.w, r.e0.w);
    d[4] = pdiff(r.a1.x, r.b1.x, r.c1.x, r.e1.x);
    d[5] = pdiff(r.a1.y, r.b1.y, r.c1.y, r.e1.y);
    d[6] = pdiff(r.a1.z, r.b1.z, r.c1.z, r.e1.z);
    d[7] = pdiff(r.a1.w, r.b1.w, r.c1.w, r.e1.w);
}

__global__ __launch_bounds__(256) void phase_loss_k(
    const float* __restrict__ er, const float* __restrict__ ei,
    const float* __restrict__ rr, const float* __restrict__ ri,
    float* __restrict__ slots)
{
    const int tid  = threadIdx.x;
    const int lane = tid & 63;
    const int wid  = (blockIdx.x << 2) | (tid >> 6);   // 0..2079
    const int b    = wid / CHUNKS;
    const int f0   = (wid - b * CHUNKS) * RPW;
    const int base = b * (NF * NT);

#define LOAD_ROW(dst, f_) do {                                   \
        const int _i = base + (f_) * NT + lane * 8;              \
        dst.a0 = *(const float4*)(er + _i);                      \
        dst.a1 = *(const float4*)(er + _i + 4);                  \
        dst.b0 = *(const float4*)(ei + _i);                      \
        dst.b1 = *(const float4*)(ei + _i + 4);                  \
        dst.c0 = *(const float4*)(rr + _i);                      \
        dst.c1 = *(const float4*)(rr + _i + 4);                  \
        dst.e0 = *(const float4*)(ri + _i);                      \
        dst.e1 = *(const float4*)(ri + _i + 4);                  \
    } while (0)

    float s = 0.f;
    float dp[8];
    Row8 cur, nxt;

    if (f0 > 0) LOAD_ROW(cur, f0 - 1);       // halo row
    LOAD_ROW(nxt, f0);                        // first owned row (prefetch)
    if (f0 > 0) {
        calc8(cur, dp);
    } else {
        #pragma unroll
        for (int k = 0; k < 8; ++k) dp[k] = 0.f;
    }

    #pragma unroll
    for (int r = 0; r < RPW; ++r) {
        const int f = f0 + r;
        if (f >= NF) break;                   // wave-uniform
        cur = nxt;
        if (r + 1 < RPW && f + 1 < NF) LOAD_ROW(nxt, f + 1);  // prefetch next row
        float d[8];
        calc8(cur, d);
        float dt = __shfl_up(d[7], 1, 64);
        if (lane == 0) dt = 0.f;              // t==0 neighbor
        #pragma unroll
        for (int k = 0; k < 8; ++k) {
            s += fabsf(d[k]);                 // ip
            s += wrap_abs(dp[k] - d[k]);      // gd (f-1 neighbor from regs)
            s += wrap_abs(dt - d[k]);         // ptd
            dt = d[k];
            dp[k] = d[k];
        }
    }
#undef LOAD_ROW

    // per-wave reduce, then tiny cross-wave combine, one plain store per block
    #pragma unroll
    for (int off = 32; off > 0; off >>= 1)
        s += __shfl_down(s, off, 64);
    __shared__ float ws4[4];
    if (lane == 0) ws4[tid >> 6] = s;
    __syncthreads();
    if (tid == 0) slots[blockIdx.x] = ws4[0] + ws4[1] + ws4[2] + ws4[3];
}

__global__ __launch_bounds__(256) void finalize_k(const float* __restrict__ slots,
                                                  float* __restrict__ out)
{
    int tid = threadIdx.x;
    float s = 0.f;
    for (int i = tid; i < NBLOCKS; i += 256) s += slots[i];
    #pragma unroll
    for (int off = 32; off > 0; off >>= 1)
        s += __shfl_down(s, off, 64);
    __shared__ float wsum[4];
    if ((tid & 63) == 0) wsum[tid >> 6] = s;
    __syncthreads();
    if (tid == 0) {
        double tot = (double)wsum[0] + (double)wsum[1] + (double)wsum[2] + (double)wsum[3];
        out[0] = (float)(tot / (double)NTOT);
    }
}

extern "C" void kernel_launch(void* const* d_in, const int* in_sizes, int n_in,
                              void* d_out, int out_size, void* d_ws, size_t ws_size,
                              hipStream_t stream) {
    const float* er = (const float*)d_in[0];
    const float* ei = (const float*)d_in[1];
    const float* rr = (const float*)d_in[2];
    const float* ri = (const float*)d_in[3];
    float* out   = (float*)d_out;
    float* slots = (float*)d_ws;              // NBLOCKS fp32, fully rewritten each call

    phase_loss_k<<<NBLOCKS, 256, 0, stream>>>(er, ei, rr, ri, slots);
    finalize_k<<<1, 256, 0, stream>>>(slots, out);
}